// Round 10
// baseline (1295.961 us; speedup 1.0000x reference)
//
#include <hip/hip_runtime.h>

#define LX 6
#define LY 6
#define NSITE 36
#define TSZ (NSITE * 2 * 256)   // transposed, zero-padded site tensors

// T table: Tt[site][s][(v + 4*l)][(v' + 4*r')] ; zero outside valid boundary dims
__device__ float g_Tt[TSZ];

__global__ __launch_bounds__(256) void build_T_kernel(const float* __restrict__ peps) {
    int idx = blockIdx.x * 256 + threadIdx.x;
    if (idx >= TSZ) return;
    int o    = idx & 15;          // v' + 4*r'
    int vl   = (idx >> 4) & 15;   // v + 4*l
    int s    = (idx >> 8) & 1;
    int site = idx >> 9;          // i*LY + j
    int i = site / LY, j = site - i * LY;
    int v = vl & 3, l = vl >> 2, vp = o & 3, rp = o >> 2;
    bool ok = (i > 0 || v == 0) && (i < LX - 1 || vp == 0) &&
              (j > 0 || l == 0) && (j < LY - 1 || rp == 0);
    // peps[i][j][s][u][d][l][r]: strides 512,256,64,16,4,1 (floats)
    g_Tt[idx] = ok ? peps[site * 512 + s * 256 + v * 64 + vp * 16 + l * 4 + rp] : 0.0f;
}

// Explicit 2-wide fp32 vectors -> v_pk_fma_f32 (gfx90a+ packed fp32).
typedef float v4f __attribute__((ext_vector_type(4)));
typedef float v2f __attribute__((ext_vector_type(2)));

union F4 { v4f v; v2f h[2]; float f[4]; };

__device__ __forceinline__ void pkfma(v2f& a, float s, v2f t) {
    a = __builtin_elementwise_fma((v2f){s, s}, t, a);
}
__device__ __forceinline__ v2f pkmul(float s, v2f t) { return (v2f){s, s} * t; }

// Bank swizzle: bijection, float4-aligned; XOR bits 5..7 and 8..10 into cluster bits 2..4.
__device__ __forceinline__ int swz(int f) {
    return f ^ ((((f >> 5) ^ (f >> 8)) & 7) << 2);
}

// Fused pair of row-steps (I, I+1) for one column.
// env flat (pre-swizzle) = v + 4*s0 + 16*s1 + 64*s2 + 256*s3 + 1024*s4 + 4096*s5.
// a = slot I (stride S1), b = slot I+1 (stride S2); thread owns one rest-combo.
// TOPB: site(I,col) has u-dim 1 -> only v=0 input row (stale v!=0 data never read).
// BOTB: site(I+1,col) has d-dim 1 -> only v''=0 output, written as SCALAR b32
// stores; v''!=0 slots left stale (next reader is a TOPB v=0-only stage, then
// pair01 stage-2 fully overwrites; col5 dot also reads v=0 only).
// Stage-1 read addresses == stage-2 write addresses: computed once into adr[4][4].
template<int I, bool TOPB, bool BOTB>
__device__ __forceinline__ void fused_pair(float* env, const float* __restrict__ T1,
                                           const float* __restrict__ T2, int tid) {
    constexpr int S1 = 1 << (2 * I + 2);
    constexpr int S2 = S1 << 2;
    const int lo = tid & ((1 << (2 * I)) - 1);
    const int hi = tid >> (2 * I);
    const int base = 4 * lo + (hi << (2 * I + 6));

    int adr[4][4];
    #pragma unroll
    for (int a = 0; a < 4; ++a)
        #pragma unroll
        for (int bb = 0; bb < 4; ++bb)
            adr[a][bb] = swz(base + a * S1 + bb * S2);

    // ---- stage 1: inter[v'][a'][b] = sum_{v,a} in[v][a][b] * T1[(v,a),(v',a')] ----
    // iL = v' 0..1, iH = v' 2..3 (v2f halves -> pk_fma)
    v2f iL[4][4], iH[4][4];
    if (TOPB) {
        #pragma unroll
        for (int a = 0; a < 4; ++a) {
            float in0[4];
            #pragma unroll
            for (int bb = 0; bb < 4; ++bb) in0[bb] = env[adr[a][bb]];
            #pragma unroll
            for (int ap = 0; ap < 4; ++ap) {
                F4 t1; t1.v = *(const v4f*)(T1 + (4 * a) * 16 + 4 * ap);   // v = 0 row
                #pragma unroll
                for (int bb = 0; bb < 4; ++bb) {
                    if (a == 0) { iL[ap][bb] = pkmul(in0[bb], t1.h[0]);
                                  iH[ap][bb] = pkmul(in0[bb], t1.h[1]); }
                    else        { pkfma(iL[ap][bb], in0[bb], t1.h[0]);
                                  pkfma(iH[ap][bb], in0[bb], t1.h[1]); }
                }
            }
        }
    } else {
        #pragma unroll
        for (int a = 0; a < 4; ++a) {
            F4 inv[4];
            #pragma unroll
            for (int bb = 0; bb < 4; ++bb) inv[bb].v = *(const v4f*)&env[adr[a][bb]];
            #pragma unroll
            for (int v = 0; v < 4; ++v) {
                #pragma unroll
                for (int ap = 0; ap < 4; ++ap) {
                    F4 t1; t1.v = *(const v4f*)(T1 + (v + 4 * a) * 16 + 4 * ap);
                    #pragma unroll
                    for (int bb = 0; bb < 4; ++bb) {
                        float iv = inv[bb].f[v];
                        if (a == 0 && v == 0) { iL[ap][bb] = pkmul(iv, t1.h[0]);
                                                iH[ap][bb] = pkmul(iv, t1.h[1]); }
                        else                  { pkfma(iL[ap][bb], iv, t1.h[0]);
                                                pkfma(iH[ap][bb], iv, t1.h[1]); }
                    }
                }
            }
        }
    }

    // ---- stage 2: out[v''][a'][b'] = sum_{v',b} inter[v'][a'][b] * T2[(v',b),(v'',b')] ----
    // All 4 a' share each T2 row load (64 loads/pair, the tile exactly once).
    if (BOTB) {
        float o[4][4];
        #pragma unroll
        for (int bb = 0; bb < 4; ++bb)
            #pragma unroll
            for (int vp = 0; vp < 4; ++vp) {
                float t2s[4];
                #pragma unroll
                for (int bp = 0; bp < 4; ++bp) t2s[bp] = T2[(vp + 4 * bb) * 16 + 4 * bp];
                #pragma unroll
                for (int ap = 0; ap < 4; ++ap) {
                    float iv = (vp < 2) ? iL[ap][bb][vp] : iH[ap][bb][vp - 2];
                    #pragma unroll
                    for (int bp = 0; bp < 4; ++bp) {
                        if (bb == 0 && vp == 0) o[ap][bp] = iv * t2s[bp];
                        else o[ap][bp] = __builtin_fmaf(iv, t2s[bp], o[ap][bp]);
                    }
                }
            }
        #pragma unroll
        for (int ap = 0; ap < 4; ++ap)
            #pragma unroll
            for (int bp = 0; bp < 4; ++bp)
                env[adr[ap][bp]] = o[ap][bp];          // scalar store, v''=0 only
    } else {
        v2f oL[4][4], oH[4][4];
        #pragma unroll
        for (int bb = 0; bb < 4; ++bb)
            #pragma unroll
            for (int vp = 0; vp < 4; ++vp) {
                F4 t2[4];
                #pragma unroll
                for (int bp = 0; bp < 4; ++bp)
                    t2[bp].v = *(const v4f*)(T2 + (vp + 4 * bb) * 16 + 4 * bp);
                #pragma unroll
                for (int ap = 0; ap < 4; ++ap) {
                    float iv = (vp < 2) ? iL[ap][bb][vp] : iH[ap][bb][vp - 2];
                    #pragma unroll
                    for (int bp = 0; bp < 4; ++bp) {
                        if (bb == 0 && vp == 0) { oL[ap][bp] = pkmul(iv, t2[bp].h[0]);
                                                  oH[ap][bp] = pkmul(iv, t2[bp].h[1]); }
                        else { pkfma(oL[ap][bp], iv, t2[bp].h[0]);
                               pkfma(oH[ap][bp], iv, t2[bp].h[1]); }
                    }
                }
            }
        #pragma unroll
        for (int ap = 0; ap < 4; ++ap)
            #pragma unroll
            for (int bp = 0; bp < 4; ++bp) {
                F4 o; o.h[0] = oL[ap][bp]; o.h[1] = oH[ap][bp];
                *(v4f*)&env[adr[ap][bp]] = o.v;
            }
    }
}

// BARRIER SCHEME (digit-arithmetic-verified, R9->R10):
//   col0 -> pair01      : same-thread dependency            -> NO barrier
//   pair01 -> pair23    : slot (v,s2,s3|s0,s1,s4,s5) written by t=s2+4s3+16s4+64s5
//                         (wave=s5), read by t'=s0+4s1+16s4+64s5 (wave=s5):
//                         SAME WAVE for every slot. Wave lockstep + in-order
//                         LDS pipe => no barrier, no fence (compiler cannot
//                         reorder must-alias dynamic LDS ops).               -> NO barrier
//   pair23 -> pair45    : producer wave=s5, reader wave=s3  -> __syncthreads
//   pair45 -> next col  : producer wave=s3, reader wave=s5  -> __syncthreads
//   col5 region         : cross-wave                        -> __syncthreads
// NO inline asm (R6 lesson: asm fences caused 10 GB scratch spills).
__global__ __launch_bounds__(256, 2) void peps_amp_kernel(const int* __restrict__ x,
                                                          float* __restrict__ out) {
    __shared__ float env[16384];
    const int tid = threadIdx.x;
    const int b = blockIdx.x;
    const int* xr = x + b * NSITE;

    // No zero-init: col0 writes all v=0 slots; pair01 (TOPB) reads only v=0 and
    // its stage-2 overwrites the full cube; col5 dot reads v=0 only.

    // ---- column 0: closed-form MPS chain -> env(r0..r5) at flat = 4*(r0+4r1+...+1024r5)
    {
        const float* A0 = g_Tt + ((0 * LY + 0) * 2 + __builtin_amdgcn_readfirstlane(xr[0 * LY])) * 256;
        const float* A1 = g_Tt + ((1 * LY + 0) * 2 + __builtin_amdgcn_readfirstlane(xr[1 * LY])) * 256;
        const float* A2 = g_Tt + ((2 * LY + 0) * 2 + __builtin_amdgcn_readfirstlane(xr[2 * LY])) * 256;
        const float* A3 = g_Tt + ((3 * LY + 0) * 2 + __builtin_amdgcn_readfirstlane(xr[3 * LY])) * 256;
        const float* A4 = g_Tt + ((4 * LY + 0) * 2 + __builtin_amdgcn_readfirstlane(xr[4 * LY])) * 256;
        const float* A5 = g_Tt + ((5 * LY + 0) * 2 + __builtin_amdgcn_readfirstlane(xr[5 * LY])) * 256;
        // A_i(r)[u][d] = T[(u + 4*0)][(d + 4r)]  (l = 0 for column 0)
        const int r2 = tid & 3, r3 = (tid >> 2) & 3, r4 = (tid >> 4) & 3, r5 = (tid >> 6) & 3;
        float w[4], w2[4];
        #pragma unroll
        for (int u = 0; u < 4; ++u) w[u] = A5[u * 16 + 4 * r5];                    // d = 0
        #pragma unroll
        for (int u = 0; u < 4; ++u) { float acc = 0;
            #pragma unroll
            for (int d = 0; d < 4; ++d) acc = __builtin_fmaf(A4[u * 16 + d + 4 * r4], w[d], acc);
            w2[u] = acc; }
        #pragma unroll
        for (int u = 0; u < 4; ++u) { float acc = 0;
            #pragma unroll
            for (int d = 0; d < 4; ++d) acc = __builtin_fmaf(A3[u * 16 + d + 4 * r3], w2[d], acc);
            w[u] = acc; }
        #pragma unroll
        for (int u = 0; u < 4; ++u) { float acc = 0;
            #pragma unroll
            for (int d = 0; d < 4; ++d) acc = __builtin_fmaf(A2[u * 16 + d + 4 * r2], w[d], acc);
            w2[u] = acc; }
        #pragma unroll
        for (int r1 = 0; r1 < 4; ++r1) {
            float u1[4];
            #pragma unroll
            for (int u = 0; u < 4; ++u) { float acc = 0;
                #pragma unroll
                for (int d = 0; d < 4; ++d) acc = __builtin_fmaf(A1[u * 16 + d + 4 * r1], w2[d], acc);
                u1[u] = acc; }
            #pragma unroll
            for (int r0 = 0; r0 < 4; ++r0) {
                float acc = 0;
                #pragma unroll
                for (int d = 0; d < 4; ++d) acc = __builtin_fmaf(A0[d + 4 * r0], u1[d], acc);
                env[swz(4 * r0 + 16 * r1 + 64 * tid)] = acc;
            }
        }
    }
    // no barrier: col0 -> pair01 is same-thread

    // ---- columns 1..4: three fused row-pairs each ----
    #pragma unroll 1
    for (int j = 1; j < LY - 1; ++j) {
        const float* T0 = g_Tt + ((0 * LY + j) * 2 + __builtin_amdgcn_readfirstlane(xr[0 * LY + j])) * 256;
        const float* T1 = g_Tt + ((1 * LY + j) * 2 + __builtin_amdgcn_readfirstlane(xr[1 * LY + j])) * 256;
        const float* T2 = g_Tt + ((2 * LY + j) * 2 + __builtin_amdgcn_readfirstlane(xr[2 * LY + j])) * 256;
        const float* T3 = g_Tt + ((3 * LY + j) * 2 + __builtin_amdgcn_readfirstlane(xr[3 * LY + j])) * 256;
        const float* T4 = g_Tt + ((4 * LY + j) * 2 + __builtin_amdgcn_readfirstlane(xr[4 * LY + j])) * 256;
        const float* T5 = g_Tt + ((5 * LY + j) * 2 + __builtin_amdgcn_readfirstlane(xr[5 * LY + j])) * 256;
        fused_pair<0, true,  false>(env, T0, T1, tid);   // -> pair23: intra-wave, no barrier
        fused_pair<2, false, false>(env, T2, T3, tid); __syncthreads();
        fused_pair<4, false, true >(env, T4, T5, tid); __syncthreads();
    }

    // ---- column 5: closed-form MPS chain + dot with env ----
    {
        const float* B0 = g_Tt + ((0 * LY + 5) * 2 + __builtin_amdgcn_readfirstlane(xr[0 * LY + 5])) * 256;
        const float* B1 = g_Tt + ((1 * LY + 5) * 2 + __builtin_amdgcn_readfirstlane(xr[1 * LY + 5])) * 256;
        const float* B2 = g_Tt + ((2 * LY + 5) * 2 + __builtin_amdgcn_readfirstlane(xr[2 * LY + 5])) * 256;
        const float* B3 = g_Tt + ((3 * LY + 5) * 2 + __builtin_amdgcn_readfirstlane(xr[3 * LY + 5])) * 256;
        const float* B4 = g_Tt + ((4 * LY + 5) * 2 + __builtin_amdgcn_readfirstlane(xr[4 * LY + 5])) * 256;
        const float* B5 = g_Tt + ((5 * LY + 5) * 2 + __builtin_amdgcn_readfirstlane(xr[5 * LY + 5])) * 256;
        // B_i(l)[u][d] = T[(u + 4l)][(d + 4*0)]  (r' = 0 for column 5)
        const int l2 = tid & 3, l3 = (tid >> 2) & 3, l4 = (tid >> 4) & 3, l5 = (tid >> 6) & 3;
        float w[4], w2[4];
        #pragma unroll
        for (int u = 0; u < 4; ++u) w[u] = B5[(u + 4 * l5) * 16];                  // d = 0
        #pragma unroll
        for (int u = 0; u < 4; ++u) { float acc = 0;
            #pragma unroll
            for (int d = 0; d < 4; ++d) acc = __builtin_fmaf(B4[(u + 4 * l4) * 16 + d], w[d], acc);
            w2[u] = acc; }
        #pragma unroll
        for (int u = 0; u < 4; ++u) { float acc = 0;
            #pragma unroll
            for (int d = 0; d < 4; ++d) acc = __builtin_fmaf(B3[(u + 4 * l3) * 16 + d], w2[d], acc);
            w[u] = acc; }
        #pragma unroll
        for (int u = 0; u < 4; ++u) { float acc = 0;
            #pragma unroll
            for (int d = 0; d < 4; ++d) acc = __builtin_fmaf(B2[(u + 4 * l2) * 16 + d], w[d], acc);
            w2[u] = acc; }
        float partial = 0.f;
        #pragma unroll
        for (int l1 = 0; l1 < 4; ++l1) {
            float u1[4];
            #pragma unroll
            for (int u = 0; u < 4; ++u) { float acc = 0;
                #pragma unroll
                for (int d = 0; d < 4; ++d) acc = __builtin_fmaf(B1[(u + 4 * l1) * 16 + d], w2[d], acc);
                u1[u] = acc; }
            #pragma unroll
            for (int l0 = 0; l0 < 4; ++l0) {
                float wv = 0.f;
                #pragma unroll
                for (int d = 0; d < 4; ++d) wv = __builtin_fmaf(B0[(4 * l0) * 16 + d], u1[d], wv);
                partial = __builtin_fmaf(env[swz(4 * l0 + 16 * l1 + 64 * tid)], wv, partial);
            }
        }
        #pragma unroll
        for (int off = 32; off; off >>= 1) partial += __shfl_down(partial, off);
        __syncthreads();                       // all env reads done before reuse
        if ((tid & 63) == 0) env[tid >> 6] = partial;
        __syncthreads();
        if (tid == 0)
            out[b] = (env[0] + env[1]) + (env[2] + env[3]);
    }
}

extern "C" void kernel_launch(void* const* d_in, const int* in_sizes, int n_in,
                              void* d_out, int out_size, void* d_ws, size_t ws_size,
                              hipStream_t stream) {
    const int* x = (const int*)d_in[0];
    const float* peps = (const float*)d_in[1];
    float* out = (float*)d_out;

    build_T_kernel<<<(TSZ + 255) / 256, 256, 0, stream>>>(peps);
    peps_amp_kernel<<<out_size, 256, 0, stream>>>(x, out);
}

// Round 11
// 933.597 us; speedup vs baseline: 1.3881x; 1.3881x over previous
//
#include <hip/hip_runtime.h>

#define LX 6
#define LY 6
#define NSITE 36
#define TSZ (NSITE * 2 * 256)   // transposed, zero-padded site tensors

// T table: Tt[site][s][(v + 4*l)][(v' + 4*r')] ; zero outside valid boundary dims
__device__ float g_Tt[TSZ];

__global__ __launch_bounds__(256) void build_T_kernel(const float* __restrict__ peps) {
    int idx = blockIdx.x * 256 + threadIdx.x;
    if (idx >= TSZ) return;
    int o    = idx & 15;          // v' + 4*r'
    int vl   = (idx >> 4) & 15;   // v + 4*l
    int s    = (idx >> 8) & 1;
    int site = idx >> 9;          // i*LY + j
    int i = site / LY, j = site - i * LY;
    int v = vl & 3, l = vl >> 2, vp = o & 3, rp = o >> 2;
    bool ok = (i > 0 || v == 0) && (i < LX - 1 || vp == 0) &&
              (j > 0 || l == 0) && (j < LY - 1 || rp == 0);
    // peps[i][j][s][u][d][l][r]: strides 512,256,64,16,4,1 (floats)
    g_Tt[idx] = ok ? peps[site * 512 + s * 256 + v * 64 + vp * 16 + l * 4 + rp] : 0.0f;
}

// Explicit 2-wide fp32 vectors -> v_pk_fma_f32 (gfx90a+ packed fp32).
typedef float v4f __attribute__((ext_vector_type(4)));
typedef float v2f __attribute__((ext_vector_type(2)));

union F4 { v4f v; v2f h[2]; float f[4]; };

__device__ __forceinline__ void pkfma(v2f& a, float s, v2f t) {
    a = __builtin_elementwise_fma((v2f){s, s}, t, a);
}
__device__ __forceinline__ v2f pkmul(float s, v2f t) { return (v2f){s, s} * t; }

// Bank swizzle: bijection, float4-aligned; XOR bits 5..7 and 8..10 into cluster bits 2..4.
__device__ __forceinline__ int swz(int f) {
    return f ^ ((((f >> 5) ^ (f >> 8)) & 7) << 2);
}

// Fused pair of row-steps (I, I+1) for one column.
// env flat (pre-swizzle) = v + 4*s0 + 16*s1 + 64*s2 + 256*s3 + 1024*s4 + 4096*s5.
// a = slot I (stride S1), b = slot I+1 (stride S2); thread owns one rest-combo.
// TOPB: site(I,col) has u-dim 1 -> only v=0 input row (stale v!=0 data never read).
// BOTB: site(I+1,col) has d-dim 1 -> only v''=0 output, written as SCALAR b32
// stores; v''!=0 slots left stale (next reader is a TOPB v=0-only stage, then
// pair01 stage-2 fully overwrites; col5 dot also reads v=0 only).
// Stage-1 read addresses == stage-2 write addresses: computed once into adr[4][4].
//
// DO NOT remove the surrounding __syncthreads() even where the dataflow is
// intra-wave (R10 lesson): the barrier also splits compiler scheduling regions;
// removing it merged two pairs' live ranges -> 200 MB of scratch spills.
// DO NOT use inline-asm fences (R6 lesson: same spill mechanism).
template<int I, bool TOPB, bool BOTB>
__device__ __forceinline__ void fused_pair(float* env, const float* __restrict__ T1,
                                           const float* __restrict__ T2, int tid) {
    constexpr int S1 = 1 << (2 * I + 2);
    constexpr int S2 = S1 << 2;
    const int lo = tid & ((1 << (2 * I)) - 1);
    const int hi = tid >> (2 * I);
    const int base = 4 * lo + (hi << (2 * I + 6));

    int adr[4][4];
    #pragma unroll
    for (int a = 0; a < 4; ++a)
        #pragma unroll
        for (int bb = 0; bb < 4; ++bb)
            adr[a][bb] = swz(base + a * S1 + bb * S2);

    // ---- stage 1: inter[v'][a'][b] = sum_{v,a} in[v][a][b] * T1[(v,a),(v',a')] ----
    // iL = v' 0..1, iH = v' 2..3 (v2f halves -> pk_fma)
    v2f iL[4][4], iH[4][4];
    if (TOPB) {
        #pragma unroll
        for (int a = 0; a < 4; ++a) {
            float in0[4];
            #pragma unroll
            for (int bb = 0; bb < 4; ++bb) in0[bb] = env[adr[a][bb]];
            #pragma unroll
            for (int ap = 0; ap < 4; ++ap) {
                F4 t1; t1.v = *(const v4f*)(T1 + (4 * a) * 16 + 4 * ap);   // v = 0 row
                #pragma unroll
                for (int bb = 0; bb < 4; ++bb) {
                    if (a == 0) { iL[ap][bb] = pkmul(in0[bb], t1.h[0]);
                                  iH[ap][bb] = pkmul(in0[bb], t1.h[1]); }
                    else        { pkfma(iL[ap][bb], in0[bb], t1.h[0]);
                                  pkfma(iH[ap][bb], in0[bb], t1.h[1]); }
                }
            }
        }
    } else {
        #pragma unroll
        for (int a = 0; a < 4; ++a) {
            F4 inv[4];
            #pragma unroll
            for (int bb = 0; bb < 4; ++bb) inv[bb].v = *(const v4f*)&env[adr[a][bb]];
            #pragma unroll
            for (int v = 0; v < 4; ++v) {
                #pragma unroll
                for (int ap = 0; ap < 4; ++ap) {
                    F4 t1; t1.v = *(const v4f*)(T1 + (v + 4 * a) * 16 + 4 * ap);
                    #pragma unroll
                    for (int bb = 0; bb < 4; ++bb) {
                        float iv = inv[bb].f[v];
                        if (a == 0 && v == 0) { iL[ap][bb] = pkmul(iv, t1.h[0]);
                                                iH[ap][bb] = pkmul(iv, t1.h[1]); }
                        else                  { pkfma(iL[ap][bb], iv, t1.h[0]);
                                                pkfma(iH[ap][bb], iv, t1.h[1]); }
                    }
                }
            }
        }
    }

    // ---- stage 2: out[v''][a'][b'] = sum_{v',b} inter[v'][a'][b] * T2[(v',b),(v'',b')] ----
    // All 4 a' share each T2 row load (64 loads/pair, the tile exactly once).
    if (BOTB) {
        float o[4][4];
        #pragma unroll
        for (int bb = 0; bb < 4; ++bb)
            #pragma unroll
            for (int vp = 0; vp < 4; ++vp) {
                float t2s[4];
                #pragma unroll
                for (int bp = 0; bp < 4; ++bp) t2s[bp] = T2[(vp + 4 * bb) * 16 + 4 * bp];
                #pragma unroll
                for (int ap = 0; ap < 4; ++ap) {
                    float iv = (vp < 2) ? iL[ap][bb][vp] : iH[ap][bb][vp - 2];
                    #pragma unroll
                    for (int bp = 0; bp < 4; ++bp) {
                        if (bb == 0 && vp == 0) o[ap][bp] = iv * t2s[bp];
                        else o[ap][bp] = __builtin_fmaf(iv, t2s[bp], o[ap][bp]);
                    }
                }
            }
        #pragma unroll
        for (int ap = 0; ap < 4; ++ap)
            #pragma unroll
            for (int bp = 0; bp < 4; ++bp)
                env[adr[ap][bp]] = o[ap][bp];          // scalar store, v''=0 only
    } else {
        v2f oL[4][4], oH[4][4];
        #pragma unroll
        for (int bb = 0; bb < 4; ++bb)
            #pragma unroll
            for (int vp = 0; vp < 4; ++vp) {
                F4 t2[4];
                #pragma unroll
                for (int bp = 0; bp < 4; ++bp)
                    t2[bp].v = *(const v4f*)(T2 + (vp + 4 * bb) * 16 + 4 * bp);
                #pragma unroll
                for (int ap = 0; ap < 4; ++ap) {
                    float iv = (vp < 2) ? iL[ap][bb][vp] : iH[ap][bb][vp - 2];
                    #pragma unroll
                    for (int bp = 0; bp < 4; ++bp) {
                        if (bb == 0 && vp == 0) { oL[ap][bp] = pkmul(iv, t2[bp].h[0]);
                                                  oH[ap][bp] = pkmul(iv, t2[bp].h[1]); }
                        else { pkfma(oL[ap][bp], iv, t2[bp].h[0]);
                               pkfma(oH[ap][bp], iv, t2[bp].h[1]); }
                    }
                }
            }
        #pragma unroll
        for (int ap = 0; ap < 4; ++ap)
            #pragma unroll
            for (int bp = 0; bp < 4; ++bp) {
                F4 o; o.h[0] = oL[ap][bp]; o.h[1] = oH[ap][bp];
                *(v4f*)&env[adr[ap][bp]] = o.v;
            }
    }
}

// 256 threads, 64 KB LDS -> 2 blocks/CU (LDS-capped, measured across R3/R5/R7);
// (256,2) keeps the VGPR cap at 256. Barrier scheme: 1 after col0, 3 per column
// (provably minimal for this decomposition: pair23->pair45 reads span all 4
// producer waves; remapping ownership to fix other edges breaks this one).
__global__ __launch_bounds__(256, 2) void peps_amp_kernel(const int* __restrict__ x,
                                                          float* __restrict__ out) {
    __shared__ float env[16384];
    const int tid = threadIdx.x;
    const int b = blockIdx.x;
    const int* xr = x + b * NSITE;

    // No zero-init: col0 writes all v=0 slots; pair01 (TOPB) reads only v=0 and
    // its stage-2 overwrites the full cube; col5 dot reads v=0 only. Stale/poison
    // data at v!=0 is never read (validated invariant, R4-R10).

    // ---- column 0: closed-form MPS chain -> env(r0..r5) at flat = 4*(r0+4r1+...+1024r5)
    {
        const float* A0 = g_Tt + ((0 * LY + 0) * 2 + __builtin_amdgcn_readfirstlane(xr[0 * LY])) * 256;
        const float* A1 = g_Tt + ((1 * LY + 0) * 2 + __builtin_amdgcn_readfirstlane(xr[1 * LY])) * 256;
        const float* A2 = g_Tt + ((2 * LY + 0) * 2 + __builtin_amdgcn_readfirstlane(xr[2 * LY])) * 256;
        const float* A3 = g_Tt + ((3 * LY + 0) * 2 + __builtin_amdgcn_readfirstlane(xr[3 * LY])) * 256;
        const float* A4 = g_Tt + ((4 * LY + 0) * 2 + __builtin_amdgcn_readfirstlane(xr[4 * LY])) * 256;
        const float* A5 = g_Tt + ((5 * LY + 0) * 2 + __builtin_amdgcn_readfirstlane(xr[5 * LY])) * 256;
        // A_i(r)[u][d] = T[(u + 4*0)][(d + 4r)]  (l = 0 for column 0)
        const int r2 = tid & 3, r3 = (tid >> 2) & 3, r4 = (tid >> 4) & 3, r5 = (tid >> 6) & 3;
        float w[4], w2[4];
        #pragma unroll
        for (int u = 0; u < 4; ++u) w[u] = A5[u * 16 + 4 * r5];                    // d = 0
        #pragma unroll
        for (int u = 0; u < 4; ++u) { float acc = 0;
            #pragma unroll
            for (int d = 0; d < 4; ++d) acc = __builtin_fmaf(A4[u * 16 + d + 4 * r4], w[d], acc);
            w2[u] = acc; }
        #pragma unroll
        for (int u = 0; u < 4; ++u) { float acc = 0;
            #pragma unroll
            for (int d = 0; d < 4; ++d) acc = __builtin_fmaf(A3[u * 16 + d + 4 * r3], w2[d], acc);
            w[u] = acc; }
        #pragma unroll
        for (int u = 0; u < 4; ++u) { float acc = 0;
            #pragma unroll
            for (int d = 0; d < 4; ++d) acc = __builtin_fmaf(A2[u * 16 + d + 4 * r2], w[d], acc);
            w2[u] = acc; }
        #pragma unroll
        for (int r1 = 0; r1 < 4; ++r1) {
            float u1[4];
            #pragma unroll
            for (int u = 0; u < 4; ++u) { float acc = 0;
                #pragma unroll
                for (int d = 0; d < 4; ++d) acc = __builtin_fmaf(A1[u * 16 + d + 4 * r1], w2[d], acc);
                u1[u] = acc; }
            #pragma unroll
            for (int r0 = 0; r0 < 4; ++r0) {
                float acc = 0;
                #pragma unroll
                for (int d = 0; d < 4; ++d) acc = __builtin_fmaf(A0[d + 4 * r0], u1[d], acc);
                env[swz(4 * r0 + 16 * r1 + 64 * tid)] = acc;
            }
        }
    }
    __syncthreads();

    // ---- columns 1..4: three fused row-pairs each ----
    #pragma unroll 1
    for (int j = 1; j < LY - 1; ++j) {
        const float* T0 = g_Tt + ((0 * LY + j) * 2 + __builtin_amdgcn_readfirstlane(xr[0 * LY + j])) * 256;
        const float* T1 = g_Tt + ((1 * LY + j) * 2 + __builtin_amdgcn_readfirstlane(xr[1 * LY + j])) * 256;
        const float* T2 = g_Tt + ((2 * LY + j) * 2 + __builtin_amdgcn_readfirstlane(xr[2 * LY + j])) * 256;
        const float* T3 = g_Tt + ((3 * LY + j) * 2 + __builtin_amdgcn_readfirstlane(xr[3 * LY + j])) * 256;
        const float* T4 = g_Tt + ((4 * LY + j) * 2 + __builtin_amdgcn_readfirstlane(xr[4 * LY + j])) * 256;
        const float* T5 = g_Tt + ((5 * LY + j) * 2 + __builtin_amdgcn_readfirstlane(xr[5 * LY + j])) * 256;
        fused_pair<0, true,  false>(env, T0, T1, tid); __syncthreads();
        fused_pair<2, false, false>(env, T2, T3, tid); __syncthreads();
        fused_pair<4, false, true >(env, T4, T5, tid); __syncthreads();
    }

    // ---- column 5: closed-form MPS chain + dot with env ----
    {
        const float* B0 = g_Tt + ((0 * LY + 5) * 2 + __builtin_amdgcn_readfirstlane(xr[0 * LY + 5])) * 256;
        const float* B1 = g_Tt + ((1 * LY + 5) * 2 + __builtin_amdgcn_readfirstlane(xr[1 * LY + 5])) * 256;
        const float* B2 = g_Tt + ((2 * LY + 5) * 2 + __builtin_amdgcn_readfirstlane(xr[2 * LY + 5])) * 256;
        const float* B3 = g_Tt + ((3 * LY + 5) * 2 + __builtin_amdgcn_readfirstlane(xr[3 * LY + 5])) * 256;
        const float* B4 = g_Tt + ((4 * LY + 5) * 2 + __builtin_amdgcn_readfirstlane(xr[4 * LY + 5])) * 256;
        const float* B5 = g_Tt + ((5 * LY + 5) * 2 + __builtin_amdgcn_readfirstlane(xr[5 * LY + 5])) * 256;
        // B_i(l)[u][d] = T[(u + 4l)][(d + 4*0)]  (r' = 0 for column 5)
        const int l2 = tid & 3, l3 = (tid >> 2) & 3, l4 = (tid >> 4) & 3, l5 = (tid >> 6) & 3;
        float w[4], w2[4];
        #pragma unroll
        for (int u = 0; u < 4; ++u) w[u] = B5[(u + 4 * l5) * 16];                  // d = 0
        #pragma unroll
        for (int u = 0; u < 4; ++u) { float acc = 0;
            #pragma unroll
            for (int d = 0; d < 4; ++d) acc = __builtin_fmaf(B4[(u + 4 * l4) * 16 + d], w[d], acc);
            w2[u] = acc; }
        #pragma unroll
        for (int u = 0; u < 4; ++u) { float acc = 0;
            #pragma unroll
            for (int d = 0; d < 4; ++d) acc = __builtin_fmaf(B3[(u + 4 * l3) * 16 + d], w2[d], acc);
            w[u] = acc; }
        #pragma unroll
        for (int u = 0; u < 4; ++u) { float acc = 0;
            #pragma unroll
            for (int d = 0; d < 4; ++d) acc = __builtin_fmaf(B2[(u + 4 * l2) * 16 + d], w[d], acc);
            w2[u] = acc; }
        float partial = 0.f;
        #pragma unroll
        for (int l1 = 0; l1 < 4; ++l1) {
            float u1[4];
            #pragma unroll
            for (int u = 0; u < 4; ++u) { float acc = 0;
                #pragma unroll
                for (int d = 0; d < 4; ++d) acc = __builtin_fmaf(B1[(u + 4 * l1) * 16 + d], w2[d], acc);
                u1[u] = acc; }
            #pragma unroll
            for (int l0 = 0; l0 < 4; ++l0) {
                float wv = 0.f;
                #pragma unroll
                for (int d = 0; d < 4; ++d) wv = __builtin_fmaf(B0[(4 * l0) * 16 + d], u1[d], wv);
                partial = __builtin_fmaf(env[swz(4 * l0 + 16 * l1 + 64 * tid)], wv, partial);
            }
        }
        #pragma unroll
        for (int off = 32; off; off >>= 1) partial += __shfl_down(partial, off);
        __syncthreads();                       // all env reads done before reuse
        if ((tid & 63) == 0) env[tid >> 6] = partial;
        __syncthreads();
        if (tid == 0)
            out[b] = (env[0] + env[1]) + (env[2] + env[3]);
    }
}

extern "C" void kernel_launch(void* const* d_in, const int* in_sizes, int n_in,
                              void* d_out, int out_size, void* d_ws, size_t ws_size,
                              hipStream_t stream) {
    const int* x = (const int*)d_in[0];
    const float* peps = (const float*)d_in[1];
    float* out = (float*)d_out;

    build_T_kernel<<<(TSZ + 255) / 256, 256, 0, stream>>>(peps);
    peps_amp_kernel<<<out_size, 256, 0, stream>>>(x, out);
}